// Round 1
// baseline (40.659 us; speedup 1.0000x reference)
//
#include <hip/hip_runtime.h>

#define NATOMS 512
#define NKPT 32
#define NPOLY 12
#define NSMAX 96
#define NSP 4
#define TI 4
#define TJ 64
#define NTHREADS 256

__global__ __launch_bounds__(NTHREADS, 4)
void dftb_kernel(const float* __restrict__ positions,
                 const int* __restrict__ species,
                 const float* __restrict__ kpoints,
                 const float* __restrict__ param,
                 const float* __restrict__ onsite,
                 const float* __restrict__ shifts,
                 float* __restrict__ out,
                 int ns)
{
    __shared__ float tab[NSMAX][64];     // [s][0..31]=cos(ang[k,s]), [32..63]=sin
    __shared__ float4 sh4[NSMAX];
    __shared__ float cpar[NSP*NSP*NPOLY];
    __shared__ float4 pjs[TJ];
    __shared__ float4 pis[TI];
    __shared__ int sjs[TJ];
    __shared__ int sis[TI];

    const int tid = threadIdx.x;
    const int bi = blockIdx.x >> 3;      // NATOMS/TJ == 8 j-tiles
    const int bj = blockIdx.x & 7;

    if (ns > NSMAX) ns = NSMAX;

    for (int idx = tid; idx < ns; idx += NTHREADS)
        sh4[idx] = make_float4(shifts[idx*3+0], shifts[idx*3+1], shifts[idx*3+2], 0.0f);
    for (int idx = tid; idx < NSP*NSP*NPOLY; idx += NTHREADS)
        cpar[idx] = param[idx];
    if (tid < TJ) {
        int j = bj*TJ + tid;
        pjs[tid] = make_float4(positions[j*3+0], positions[j*3+1], positions[j*3+2], 0.0f);
        sjs[tid] = species[j];
    } else if (tid < TJ + TI) {
        int r = tid - TJ;
        int i = bi*TI + r;
        pis[r] = make_float4(positions[i*3+0], positions[i*3+1], positions[i*3+2], 0.0f);
        sis[r] = species[i];
    }
    // phase table: ang[k,s] = 2*pi * (kpoints[k]*0.2) . shifts[s]  (lattice = diag(5))
    for (int idx = tid; idx < ns*NKPT; idx += NTHREADS) {
        int s = idx >> 5;
        int k = idx & 31;
        float kcx = kpoints[k*3+0] * 0.2f;
        float kcy = kpoints[k*3+1] * 0.2f;
        float kcz = kpoints[k*3+2] * 0.2f;
        float d = (kcx*shifts[s*3+0] + kcy*shifts[s*3+1]) + kcz*shifts[s*3+2];
        float ang = 6.283185307179586f * d;
        float sn, cs;
        sincosf(ang, &sn, &cs);
        tab[s][k]      = cs;
        tab[s][32 + k] = sn;
    }
    __syncthreads();

    const int li = tid >> 6;             // wave index = i within tile (wave-uniform)
    const int lj = tid & 63;             // lane = j within tile (coalesced)
    const int i = bi*TI + li;
    const int j = bj*TJ + lj;
    const float4 pi4 = pis[li];
    const float4 pj4 = pjs[lj];
    const int si = sis[li];
    const int sj = sjs[lj];

    float c[NPOLY];
    #pragma unroll
    for (int q = 0; q < NPOLY; ++q) c[q] = cpar[(si*NSP + sj)*NPOLY + q];

    float accR[NKPT], accI[NKPT];
    #pragma unroll
    for (int k = 0; k < NKPT; ++k) { accR[k] = 0.0f; accI[k] = 0.0f; }

    for (int s = 0; s < ns; ++s) {
        const float4 sh = sh4[s];
        // match numpy order exactly: (pos_j + shift) - pos_i ; (x^2 + y^2) + z^2, no FMA contraction
        float dx = (pj4.x + sh.x) - pi4.x;
        float dy = (pj4.y + sh.y) - pi4.y;
        float dz = (pj4.z + sh.z) - pi4.z;
        float dr2 = (__fmul_rn(dx,dx) + __fmul_rn(dy,dy)) + __fmul_rn(dz,dz);
        float dr = sqrtf(dr2);           // HIP default: correctly-rounded fp32 sqrt
        bool ok = (dr > 0.1f) && (dr <= 6.0f);
        if (__ballot(ok) == 0ULL) continue;   // exact skip: fmaf(0,c,acc) == acc
        float x = dr * 1.8897261258369282f;
        float y = c[NPOLY-1];
        #pragma unroll
        for (int q = NPOLY-2; q >= 0; --q) y = fmaf(y, x, c[q]);
        float V = ok ? y : 0.0f;
        const float4* tp = (const float4*)(&tab[s][0]);   // uniform address -> LDS broadcast
        #pragma unroll
        for (int q = 0; q < 8; ++q) {
            float4 cv = tp[q];
            accR[4*q+0] = fmaf(V, cv.x, accR[4*q+0]);
            accR[4*q+1] = fmaf(V, cv.y, accR[4*q+1]);
            accR[4*q+2] = fmaf(V, cv.z, accR[4*q+2]);
            accR[4*q+3] = fmaf(V, cv.w, accR[4*q+3]);
        }
        #pragma unroll
        for (int q = 0; q < 8; ++q) {
            float4 sv = tp[8+q];
            accI[4*q+0] = fmaf(V, sv.x, accI[4*q+0]);
            accI[4*q+1] = fmaf(V, sv.y, accI[4*q+1]);
            accI[4*q+2] = fmaf(V, sv.z, accI[4*q+2]);
            accI[4*q+3] = fmaf(V, sv.w, accI[4*q+3]);
        }
    }

    const float oi = (i == j) ? onsite[si] : 0.0f;
    float* outR = out + (size_t)i*NATOMS + j;
    float* outI = outR + (size_t)NKPT*NATOMS*NATOMS;
    #pragma unroll
    for (int k = 0; k < NKPT; ++k) {
        outR[(size_t)k*NATOMS*NATOMS] = accR[k] + oi;   // Hr (+onsite on diagonal)
        outI[(size_t)k*NATOMS*NATOMS] = accI[k];        // Hi
    }
}

extern "C" void kernel_launch(void* const* d_in, const int* in_sizes, int n_in,
                              void* d_out, int out_size, void* d_ws, size_t ws_size,
                              hipStream_t stream) {
    const float* positions = (const float*)d_in[0];
    const int*   species   = (const int*)d_in[1];
    const float* kpoints   = (const float*)d_in[2];
    const float* param     = (const float*)d_in[3];
    const float* onsite    = (const float*)d_in[4];
    const float* shifts    = (const float*)d_in[5];
    int ns = in_sizes[5] / 3;
    float* out = (float*)d_out;

    dim3 grid((NATOMS/TI) * (NATOMS/TJ));   // 128 * 8 = 1024 blocks
    dftb_kernel<<<grid, NTHREADS, 0, stream>>>(positions, species, kpoints,
                                               param, onsite, shifts, out, ns);
}